// Round 3
// baseline (253.848 us; speedup 1.0000x reference)
//
#include <hip/hip_runtime.h>
#include <hip/hip_bf16.h>

// Problem constants (from reference setup_inputs): B=8, N=2048, D=512
#define PB 8
#define PN 2048
#define PD 512
#define P_ASEM 0.6f

// Native clang vector type — required by __builtin_nontemporal_* (HIP's
// float4 is a class and is rejected).
typedef float v4f __attribute__((ext_vector_type(4)));

// ---------------------------------------------------------------------------
// Kernel 1: per-row dots. si[r] = x[r,:].Wi, sj[r] = x[r,:].Wj for r in [0,B*N)
// One wave per row; 2x v4f per lane; 64-lane butterfly reduction.
// ---------------------------------------------------------------------------
__global__ __launch_bounds__(256) void row_dots_kernel(
    const float* __restrict__ x,   // [B*N, D]
    const float* __restrict__ W,   // [2*D]
    float* __restrict__ si,        // [B*N]
    float* __restrict__ sj)        // [B*N]
{
    const int wave = threadIdx.x >> 6;            // 0..3
    const int lane = threadIdx.x & 63;
    const int row  = blockIdx.x * 4 + wave;       // grid = B*N/4

    const v4f* xr = (const v4f*)(x + (size_t)row * PD);
    const v4f* Wi = (const v4f*)(W);
    const v4f* Wj = (const v4f*)(W + PD);

    // D = 512 floats = 128 v4f; 64 lanes -> 2 v4f per lane
    v4f a0  = __builtin_nontemporal_load(xr + lane);
    v4f a1  = __builtin_nontemporal_load(xr + lane + 64);
    v4f wi0 = Wi[lane];
    v4f wi1 = Wi[lane + 64];
    v4f wj0 = Wj[lane];
    v4f wj1 = Wj[lane + 64];

    float acc_i = a0.x*wi0.x + a0.y*wi0.y + a0.z*wi0.z + a0.w*wi0.w
                + a1.x*wi1.x + a1.y*wi1.y + a1.z*wi1.z + a1.w*wi1.w;
    float acc_j = a0.x*wj0.x + a0.y*wj0.y + a0.z*wj0.z + a0.w*wj0.w
                + a1.x*wj1.x + a1.y*wj1.y + a1.z*wj1.z + a1.w*wj1.w;

    #pragma unroll
    for (int off = 32; off > 0; off >>= 1) {
        acc_i += __shfl_down(acc_i, off, 64);
        acc_j += __shfl_down(acc_j, off, 64);
    }
    if (lane == 0) {
        si[row] = acc_i;
        sj[row] = acc_j;
    }
}

// ---------------------------------------------------------------------------
// Kernel 2: out[b,i,j] = 0.6*sigmoid(si[b,i]+sj[b,j]+b0) + 0.4*adj[b,i,j]
// 2x v4f per thread; nontemporal streaming for adj/out (no reuse, keep L2
// clean); v_rcp_f32 instead of full-precision divide (1 ulp, threshold has
// 5x headroom per round-1 absmax).
// ---------------------------------------------------------------------------
__device__ __forceinline__ float fsigmoid(float t) {
    return __frcp_rn(1.0f + __expf(-t));
}

__global__ __launch_bounds__(256) void blend_kernel(
    const float* __restrict__ adj,  // [B*N*N]
    const float* __restrict__ si,   // [B*N]
    const float* __restrict__ sj,   // [B*N]
    const float* __restrict__ bptr, // [1]
    float* __restrict__ out)        // [B*N*N]
{
    // each thread: 2 v4f (8 floats), consecutive in j
    const size_t t  = (size_t)blockIdx.x * blockDim.x + threadIdx.x;
    const size_t o0 = t * 2;               // first v4f index
    const int row   = (int)(o0 >> 9);      // / (N/4=512): combined b*N+i row
    const int jc    = (int)(o0 & 511);     // v4f column within row
    const int bidx  = row >> 11;           // / N -> batch

    const float s = si[row] + bptr[0];
    const v4f* sjr = (const v4f*)(sj + (size_t)bidx * PN);
    const v4f sv0 = sjr[jc];
    const v4f sv1 = sjr[jc + 1];
    const v4f av0 = __builtin_nontemporal_load((const v4f*)adj + o0);
    const v4f av1 = __builtin_nontemporal_load((const v4f*)adj + o0 + 1);

    v4f r0, r1;
    r0.x = P_ASEM * fsigmoid(s + sv0.x) + (1.0f - P_ASEM) * av0.x;
    r0.y = P_ASEM * fsigmoid(s + sv0.y) + (1.0f - P_ASEM) * av0.y;
    r0.z = P_ASEM * fsigmoid(s + sv0.z) + (1.0f - P_ASEM) * av0.z;
    r0.w = P_ASEM * fsigmoid(s + sv0.w) + (1.0f - P_ASEM) * av0.w;
    r1.x = P_ASEM * fsigmoid(s + sv1.x) + (1.0f - P_ASEM) * av1.x;
    r1.y = P_ASEM * fsigmoid(s + sv1.y) + (1.0f - P_ASEM) * av1.y;
    r1.z = P_ASEM * fsigmoid(s + sv1.z) + (1.0f - P_ASEM) * av1.z;
    r1.w = P_ASEM * fsigmoid(s + sv1.w) + (1.0f - P_ASEM) * av1.w;

    __builtin_nontemporal_store(r0, (v4f*)out + o0);
    __builtin_nontemporal_store(r1, (v4f*)out + o0 + 1);
}

extern "C" void kernel_launch(void* const* d_in, const int* in_sizes, int n_in,
                              void* d_out, int out_size, void* d_ws, size_t ws_size,
                              hipStream_t stream) {
    const float* x   = (const float*)d_in[0];  // [8,2048,512]
    const float* adj = (const float*)d_in[1];  // [8,2048,2048]
    const float* W   = (const float*)d_in[2];  // [1,1024]
    const float* b   = (const float*)d_in[3];  // [1]
    float* out = (float*)d_out;

    float* si = (float*)d_ws;            // B*N = 16384 floats
    float* sj = si + (PB * PN);          // B*N = 16384 floats

    // Kernel 1: B*N/4 = 4096 blocks (4 waves = 4 rows each)
    row_dots_kernel<<<(PB * PN) / 4, 256, 0, stream>>>(x, W, si, sj);

    // Kernel 2: B*N*N/8 threads (8 floats each), 16384 blocks of 256
    const size_t nthreads = (size_t)PB * PN * PN / 8;
    blend_kernel<<<(int)(nthreads / 256), 256, 0, stream>>>(adj, si, sj, b, out);
}